// Round 1
// baseline (970.660 us; speedup 1.0000x reference)
//
#include <hip/hip_runtime.h>
#include <stdint.h>

// SelfAttention: B=4, S=4096, D=768, causal, fp32 in/out, bf16 MFMA compute.
// ws layout (bf16 elements):
//   qb  [B*S*D]           offset 0
//   kb  [B*S*D]           offset 12582912
//   vt  [B][D][S]         offset 25165824   (V transposed for PV B-frags)
//   xb  [B*S*D]           offset 37748736   (x cast to bf16)
//   wb  [3][D][D]         offset 50331648   (Wq|Wk|Wv cast to bf16)
// total = (50331648 + 1769472) * 2 bytes = 104,202,240 B

#define SEQ 4096
#define DIM 768

typedef __attribute__((ext_vector_type(8))) short short8;
typedef __attribute__((ext_vector_type(8))) unsigned short ushort8;
typedef __attribute__((ext_vector_type(4))) unsigned short ushort4v;
typedef __attribute__((ext_vector_type(4))) float fx4;

#define MFMA16(a, b, c) __builtin_amdgcn_mfma_f32_16x16x32_bf16((a), (b), (c), 0, 0, 0)

__device__ __forceinline__ unsigned short f2bf(float f) {
  union { float f; unsigned int u; } v; v.f = f;
  return (unsigned short)((v.u + 0x7fffu + ((v.u >> 16) & 1u)) >> 16);
}
__device__ __forceinline__ float bf2f(unsigned short u) {
  union { unsigned int u; float f; } v; v.u = ((unsigned int)u) << 16;
  return v.f;
}

// ---------- kernel 0a: x fp32 -> bf16 (12,582,912 elems, 8/thread) ----------
__global__ void cvt_x(const float* __restrict__ x, unsigned short* __restrict__ xb) {
  const int i = (blockIdx.x * 256 + threadIdx.x) * 8;
  fx4 a = *(const fx4*)(x + i);
  fx4 b = *(const fx4*)(x + i + 4);
  ushort8 o;
#pragma unroll
  for (int c = 0; c < 4; c++) { o[c] = f2bf(a[c]); o[c + 4] = f2bf(b[c]); }
  *(ushort8*)(xb + i) = o;
}

// ---------- kernel 0b: Wq|Wk|Wv fp32 -> bf16 (3*589824 elems) ----------
__global__ void cvt_w(const float* __restrict__ wq, const float* __restrict__ wk,
                      const float* __restrict__ wv, unsigned short* __restrict__ wb) {
  const int i = (blockIdx.x * 256 + threadIdx.x) * 8;
  const int which = i / (DIM * DIM);
  const int off = i - which * (DIM * DIM);
  const float* src = (which == 0) ? wq : (which == 1) ? wk : wv;
  fx4 a = *(const fx4*)(src + off);
  fx4 b = *(const fx4*)(src + off + 4);
  ushort8 o;
#pragma unroll
  for (int c = 0; c < 4; c++) { o[c] = f2bf(a[c]); o[c + 4] = f2bf(b[c]); }
  *(ushort8*)(wb + i) = o;
}

// ---------- kernel 1: QKV projection  y[s][e] = sum_d x[s,d]*W[e,d] ----------
// block tile 64(m) x 128(n), 4 waves each 32x64. grid (256, 18): y-dim picks
// (which W, e0). Q/K stored [s][e] via LDS transpose; V stored transposed [e][s].
__global__ __launch_bounds__(256, 2)
void qkv_proj(const unsigned short* __restrict__ xb, const unsigned short* __restrict__ wb,
              unsigned short* __restrict__ qb, unsigned short* __restrict__ kb,
              unsigned short* __restrict__ vt) {
  __shared__ unsigned short ys[64][136];  // +8 pad keeps 16B align, breaks bank stride
  const int mb = blockIdx.x, nb = blockIdx.y;
  const int which = nb / 6;
  const int e0 = (nb % 6) * 128;
  const int m0 = mb * 64;
  const int tid = threadIdx.x;
  const int w = tid >> 6, lane = tid & 63, ln = lane & 15, quad = lane >> 4;
  const int wrow = (w >> 1) * 32, wcol = (w & 1) * 64;

  const unsigned short* W = wb + (size_t)which * (DIM * DIM);

  fx4 acc[2][4];
#pragma unroll
  for (int mt = 0; mt < 2; mt++)
#pragma unroll
    for (int nt = 0; nt < 4; nt++) acc[mt][nt] = (fx4)0.0f;

  const unsigned short* arow[2];
  const unsigned short* brow[4];
#pragma unroll
  for (int mt = 0; mt < 2; mt++)
    arow[mt] = xb + (size_t)(m0 + wrow + mt * 16 + ln) * DIM + quad * 8;
#pragma unroll
  for (int nt = 0; nt < 4; nt++)
    brow[nt] = W + (size_t)(e0 + wcol + nt * 16 + ln) * DIM + quad * 8;

  for (int kk = 0; kk < DIM; kk += 32) {
    short8 a0 = *(const short8*)(arow[0] + kk);
    short8 a1 = *(const short8*)(arow[1] + kk);
#pragma unroll
    for (int nt = 0; nt < 4; nt++) {
      short8 bf = *(const short8*)(brow[nt] + kk);
      acc[0][nt] = MFMA16(a0, bf, acc[0][nt]);
      acc[1][nt] = MFMA16(a1, bf, acc[1][nt]);
    }
  }

  if (which == 2) {
    // V: direct transposed store; lane holds 4 consecutive s at fixed e -> 8B packed
#pragma unroll
    for (int mt = 0; mt < 2; mt++)
#pragma unroll
      for (int nt = 0; nt < 4; nt++) {
        const int s = m0 + wrow + mt * 16 + quad * 4;
        const int e = e0 + wcol + nt * 16 + ln;
        const int bb = s >> 12, si = s & 4095;
        ushort4v p;
#pragma unroll
        for (int r = 0; r < 4; r++) p[r] = f2bf(acc[mt][nt][r]);
        *(ushort4v*)(vt + ((size_t)bb * DIM + e) * SEQ + si) = p;
      }
  } else {
    // Q/K: C-layout -> LDS -> coalesced 16B row stores
#pragma unroll
    for (int mt = 0; mt < 2; mt++)
#pragma unroll
      for (int nt = 0; nt < 4; nt++) {
        const int row = wrow + mt * 16 + quad * 4;
        const int col = wcol + nt * 16 + ln;
#pragma unroll
        for (int r = 0; r < 4; r++) ys[row + r][col] = f2bf(acc[mt][nt][r]);
      }
    __syncthreads();
    unsigned short* dst = (which == 0) ? qb : kb;
#pragma unroll
    for (int p = 0; p < 4; p++) {
      const int tt = p * 256 + tid;
      const int row = tt >> 4, chunk = tt & 15;
      ushort8 v = *(const ushort8*)&ys[row][chunk * 8];
      *(ushort8*)(dst + (size_t)(m0 + row) * DIM + e0 + chunk * 8) = v;
    }
  }
}

// ---------- kernel 2: causal flash attention ----------
// 512 blocks: batch = bi&3, q-tile j = 127-(bi>>2) (longest work dispatched first).
// 4 waves split D (192 each). Per k-tile (32 keys): partial QK^T per wave ->
// LDS reduce -> distributed online softmax -> P (bf16, LDS) @ V-slice.
__global__ __launch_bounds__(256, 2)
void attn(const unsigned short* __restrict__ qb, const unsigned short* __restrict__ kb,
          const unsigned short* __restrict__ vt, float* __restrict__ out) {
  __shared__ float sred[4][32][33];       // +1 pad: phase-2 reads conflict-free
  __shared__ unsigned short pbuf[32][40]; // +8 pad keeps 16B align for b128 reads
  __shared__ float row_m[32], row_l[32], row_a[32];

  const int bi = blockIdx.x;
  const int b = bi & 3;
  const int j = 127 - (bi >> 2);
  const int q0 = j * 32;
  const int nk = j + 1;
  const int tid = threadIdx.x;
  const int w = tid >> 6, lane = tid & 63, ln = lane & 15, quad = lane >> 4;

  const size_t qkbase = (size_t)b * SEQ * DIM;
  const size_t vtbase = (size_t)b * DIM * SEQ;
  const float scale = 0.03608439182435161f;  // 1/sqrt(768)

  // Q fragments for this wave's 192-wide D slice: 12 frags, in registers
  short8 qf[2][6];
  {
    const unsigned short* qp = qb + qkbase + (size_t)(q0 + ln) * DIM + w * 192 + quad * 8;
#pragma unroll
    for (int mt = 0; mt < 2; mt++)
#pragma unroll
      for (int ks = 0; ks < 6; ks++)
        qf[mt][ks] = *(const short8*)(qp + mt * 16 * DIM + ks * 32);
  }

  fx4 acc[2][12];
#pragma unroll
  for (int mt = 0; mt < 2; mt++)
#pragma unroll
    for (int n = 0; n < 12; n++) acc[mt][n] = (fx4)0.0f;

  if (tid < 32) { row_m[tid] = -1e30f; row_l[tid] = 0.0f; }
  __syncthreads();

  for (int kt = 0; kt < nk; kt++) {
    const int k0 = kt * 32;

    // ---- phase 1: partial scores over this wave's D slice ----
    fx4 sacc[2][2];
#pragma unroll
    for (int mt = 0; mt < 2; mt++)
#pragma unroll
      for (int n = 0; n < 2; n++) sacc[mt][n] = (fx4)0.0f;
    const unsigned short* kp = kb + qkbase + (size_t)(k0 + ln) * DIM + w * 192 + quad * 8;
#pragma unroll
    for (int n = 0; n < 2; n++)
#pragma unroll
      for (int ks = 0; ks < 6; ks++) {
        short8 kf = *(const short8*)(kp + n * 16 * DIM + ks * 32);
        sacc[0][n] = MFMA16(qf[0][ks], kf, sacc[0][n]);
        sacc[1][n] = MFMA16(qf[1][ks], kf, sacc[1][n]);
      }
#pragma unroll
    for (int mt = 0; mt < 2; mt++)
#pragma unroll
      for (int n = 0; n < 2; n++)
#pragma unroll
        for (int r = 0; r < 4; r++)
          sred[w][mt * 16 + quad * 4 + r][n * 16 + ln] = sacc[mt][n][r];
    __syncthreads();

    // ---- phase 2: cross-wave reduce + online softmax (8 lanes per row) ----
    {
      const int row = w * 8 + (lane >> 3);
      const int cg = lane & 7;
      const int qa = q0 + row;
      float s[4];
      float tmax = -1e30f;
#pragma unroll
      for (int c = 0; c < 4; c++) {
        const int col = cg * 4 + c;
        float v = sred[0][row][col] + sred[1][row][col] + sred[2][row][col] + sred[3][row][col];
        v *= scale;
        if (k0 + col > qa) v = -1e30f;
        s[c] = v;
        tmax = fmaxf(tmax, v);
      }
      tmax = fmaxf(tmax, __shfl_xor(tmax, 1));
      tmax = fmaxf(tmax, __shfl_xor(tmax, 2));
      tmax = fmaxf(tmax, __shfl_xor(tmax, 4));
      const float m_old = row_m[row];
      const float m_new = fmaxf(m_old, tmax);
      const float alpha = __expf(m_old - m_new);
      ushort4v pk;
      float psum = 0.0f;
#pragma unroll
      for (int c = 0; c < 4; c++) {
        const float p = __expf(s[c] - m_new);
        pk[c] = f2bf(p);
        psum += bf2f(pk[c]);  // keep numerator/denominator consistently rounded
      }
      psum += __shfl_xor(psum, 1);
      psum += __shfl_xor(psum, 2);
      psum += __shfl_xor(psum, 4);
      if (cg == 0) {
        row_m[row] = m_new;
        row_l[row] = alpha * row_l[row] + psum;
        row_a[row] = alpha;
      }
      *(ushort4v*)&pbuf[row][cg * 4] = pk;
    }
    __syncthreads();

    // ---- phase 3: O rescale (skipped when all alpha==1) + P @ V-slice ----
    {
      float al0[4], al1[4];
      bool need = false;
#pragma unroll
      for (int r = 0; r < 4; r++) {
        al0[r] = row_a[quad * 4 + r];
        al1[r] = row_a[16 + quad * 4 + r];
        need = need || (al0[r] != 1.0f) || (al1[r] != 1.0f);
      }
      if (__any(need)) {
#pragma unroll
        for (int n = 0; n < 12; n++)
#pragma unroll
          for (int r = 0; r < 4; r++) {
            acc[0][n][r] *= al0[r];
            acc[1][n][r] *= al1[r];
          }
      }
      short8 pa0 = *(const short8*)&pbuf[ln][quad * 8];
      short8 pa1 = *(const short8*)&pbuf[16 + ln][quad * 8];
      const unsigned short* vp = vt + vtbase + (size_t)(w * 192 + ln) * SEQ + k0 + quad * 8;
#pragma unroll
      for (int n = 0; n < 12; n++) {
        short8 vf = *(const short8*)(vp + n * 16 * SEQ);
        acc[0][n] = MFMA16(pa0, vf, acc[0][n]);
        acc[1][n] = MFMA16(pa1, vf, acc[1][n]);
      }
    }
  }

  // ---- epilogue: O / l ----
#pragma unroll
  for (int mt = 0; mt < 2; mt++)
#pragma unroll
    for (int r = 0; r < 4; r++) {
      const int row = mt * 16 + quad * 4 + r;
      const float linv = 1.0f / row_l[row];
      float* orow = out + (size_t)(b * SEQ + q0 + row) * DIM + w * 192 + ln;
#pragma unroll
      for (int n = 0; n < 12; n++) orow[n * 16] = acc[mt][n][r] * linv;
    }
}

extern "C" void kernel_launch(void* const* d_in, const int* in_sizes, int n_in,
                              void* d_out, int out_size, void* d_ws, size_t ws_size,
                              hipStream_t stream) {
  const float* x = (const float*)d_in[0];
  const float* wq = (const float*)d_in[1];
  const float* wk = (const float*)d_in[2];
  const float* wv = (const float*)d_in[3];
  float* out = (float*)d_out;

  unsigned short* qb = (unsigned short*)d_ws;
  unsigned short* kb = qb + 12582912;
  unsigned short* vt = kb + 12582912;
  unsigned short* xb = vt + 12582912;
  unsigned short* wb = xb + 12582912;

  cvt_x<<<6144, 256, 0, stream>>>(x, xb);
  cvt_w<<<864, 256, 0, stream>>>(wq, wk, wv, wb);
  qkv_proj<<<dim3(256, 18), 256, 0, stream>>>(xb, wb, qb, kb, vt);
  attn<<<512, 256, 0, stream>>>(qb, kb, vt, out);
}

// Round 2
// 743.536 us; speedup vs baseline: 1.3055x; 1.3055x over previous
//
#include <hip/hip_runtime.h>
#include <stdint.h>

// SelfAttention: B=4, S=4096, D=768, causal, fp32 in/out, bf16 MFMA compute.
// ws layout (bf16 elements): qb | kb | vt[B][D][S] | xb | wb  (104 MB total)

#define SEQ 4096
#define DIM 768

typedef __attribute__((ext_vector_type(8))) short short8;
typedef __attribute__((ext_vector_type(8))) unsigned short ushort8;
typedef __attribute__((ext_vector_type(4))) unsigned short ushort4v;
typedef __attribute__((ext_vector_type(4))) float fx4;
typedef unsigned short ushort;

#define MFMA16(a, b, c) __builtin_amdgcn_mfma_f32_16x16x32_bf16((a), (b), (c), 0, 0, 0)

__device__ __forceinline__ ushort f2bf(float f) {
  union { float f; unsigned int u; } v; v.f = f;
  return (ushort)((v.u + 0x7fffu + ((v.u >> 16) & 1u)) >> 16);
}
__device__ __forceinline__ float bf2f(ushort u) {
  union { unsigned int u; float f; } v; v.u = ((unsigned int)u) << 16;
  return v.f;
}
__device__ __forceinline__ void gload_lds16(const ushort* g, ushort* l) {
  __builtin_amdgcn_global_load_lds(
      (const __attribute__((address_space(1))) void*)g,
      (__attribute__((address_space(3))) void*)l, 16, 0, 0);
}

// ---------- cvt kernels ----------
__global__ void cvt_x(const float* __restrict__ x, ushort* __restrict__ xb) {
  const int i = (blockIdx.x * 256 + threadIdx.x) * 8;
  fx4 a = *(const fx4*)(x + i);
  fx4 b = *(const fx4*)(x + i + 4);
  ushort8 o;
#pragma unroll
  for (int c = 0; c < 4; c++) { o[c] = f2bf(a[c]); o[c + 4] = f2bf(b[c]); }
  *(ushort8*)(xb + i) = o;
}

__global__ void cvt_w(const float* __restrict__ wq, const float* __restrict__ wk,
                      const float* __restrict__ wv, ushort* __restrict__ wb) {
  const int i = (blockIdx.x * 256 + threadIdx.x) * 8;
  const int which = i / (DIM * DIM);
  const int off = i - which * (DIM * DIM);
  const float* src = (which == 0) ? wq : (which == 1) ? wk : wv;
  fx4 a = *(const fx4*)(src + off);
  fx4 b = *(const fx4*)(src + off + 4);
  ushort8 o;
#pragma unroll
  for (int c = 0; c < 4; c++) { o[c] = f2bf(a[c]); o[c + 4] = f2bf(b[c]); }
  *(ushort8*)(wb + i) = o;
}

// ---------- kernel 1: QKV projection, m97-style 128x128 tile ----------
// grid (128, 18): x = m-tile (128 rows), y = which*6 + e-tile.
// global_load_lds staging, XOR k-group swizzle, 16 MFMA/wave/k-step.
__global__ __launch_bounds__(256, 4)
void qkv_proj(const ushort* __restrict__ xb, const ushort* __restrict__ wb,
              ushort* __restrict__ qb, ushort* __restrict__ kb,
              ushort* __restrict__ vt) {
  __shared__ ushort smem[17408];  // As[0..4095] | Bs[4096..8191]; epilogue ys[128][136]
  ushort* As = smem;
  ushort* Bs = smem + 4096;

  const int mb = blockIdx.x, nb = blockIdx.y;
  const int which = nb / 6;
  const int e0 = (nb % 6) * 128;
  const int m0 = mb * 128;
  const int tid = threadIdx.x;
  const int w = tid >> 6, lane = tid & 63, ln = lane & 15, quad = lane >> 4;
  const int wm = (w >> 1) * 64, wn = (w & 1) * 64;

  const ushort* W = wb + (size_t)which * (DIM * DIM);

  // staging: wave w covers chunks [w*128, w*128+128); chunk c = 16B at LDS byte c*16
  // chunk c holds row R=c>>2, logical k-group kl = (c&3) ^ ((R>>1)&3)  (XOR swizzle)
  const int c0 = w * 128 + lane;
  const int c1 = c0 + 64;
  const int R0 = c0 >> 2, kl0 = (c0 & 3) ^ ((R0 >> 1) & 3);
  const int R1 = c1 >> 2, kl1 = (c1 & 3) ^ ((R1 >> 1) & 3);
  const ushort* ag0 = xb + (size_t)(m0 + R0) * DIM + kl0 * 8;
  const ushort* ag1 = xb + (size_t)(m0 + R1) * DIM + kl1 * 8;
  const ushort* bg0 = W + (size_t)(e0 + R0) * DIM + kl0 * 8;
  const ushort* bg1 = W + (size_t)(e0 + R1) * DIM + kl1 * 8;
  ushort* al0 = As + (size_t)(w * 128) * 8;      // wave-uniform LDS bases
  ushort* al1 = As + (size_t)(w * 128 + 64) * 8;
  ushort* bl0 = Bs + (size_t)(w * 128) * 8;
  ushort* bl1 = Bs + (size_t)(w * 128 + 64) * 8;

  // fragment read offsets (constant over k-steps): chunk = R*4 + (quad ^ ((ln>>1)&3))
  const int sw = quad ^ ((ln >> 1) & 3);
  int aoff[4], boff[4];
#pragma unroll
  for (int mt = 0; mt < 4; mt++) aoff[mt] = ((wm + mt * 16 + ln) * 4 + sw) * 8;
#pragma unroll
  for (int nt = 0; nt < 4; nt++) boff[nt] = ((wn + nt * 16 + ln) * 4 + sw) * 8;

  fx4 acc[4][4];
#pragma unroll
  for (int mt = 0; mt < 4; mt++)
#pragma unroll
    for (int nt = 0; nt < 4; nt++) acc[mt][nt] = (fx4)0.0f;

  for (int kk = 0; kk < DIM; kk += 32) {
    gload_lds16(ag0 + kk, al0);
    gload_lds16(ag1 + kk, al1);
    gload_lds16(bg0 + kk, bl0);
    gload_lds16(bg1 + kk, bl1);
    __syncthreads();
    short8 af[4], bf[4];
#pragma unroll
    for (int mt = 0; mt < 4; mt++) af[mt] = *(const short8*)(As + aoff[mt]);
#pragma unroll
    for (int nt = 0; nt < 4; nt++) bf[nt] = *(const short8*)(Bs + boff[nt]);
#pragma unroll
    for (int mt = 0; mt < 4; mt++)
#pragma unroll
      for (int nt = 0; nt < 4; nt++)
        acc[mt][nt] = MFMA16(af[mt], bf[nt], acc[mt][nt]);
    __syncthreads();
  }

  if (which == 2) {
    // V: direct transposed store [e][s], 4 consecutive s per lane (8B)
#pragma unroll
    for (int mt = 0; mt < 4; mt++)
#pragma unroll
      for (int nt = 0; nt < 4; nt++) {
        const int s = m0 + wm + mt * 16 + quad * 4;
        const int e = e0 + wn + nt * 16 + ln;
        const int bb = s >> 12, si = s & 4095;
        ushort4v p;
#pragma unroll
        for (int r = 0; r < 4; r++) p[r] = f2bf(acc[mt][nt][r]);
        *(ushort4v*)(vt + ((size_t)bb * DIM + e) * SEQ + si) = p;
      }
  } else {
    // Q/K: C-layout -> LDS (alias smem, k-loop ended with a barrier) -> 16B stores
#pragma unroll
    for (int mt = 0; mt < 4; mt++)
#pragma unroll
      for (int nt = 0; nt < 4; nt++)
#pragma unroll
        for (int r = 0; r < 4; r++)
          smem[(wm + mt * 16 + quad * 4 + r) * 136 + wn + nt * 16 + ln] =
              f2bf(acc[mt][nt][r]);
    __syncthreads();
    ushort* dst = (which == 0) ? qb : kb;
#pragma unroll
    for (int p = 0; p < 8; p++) {
      const int tt = p * 256 + tid;
      const int row = tt >> 4, col = (tt & 15) * 8;
      ushort8 v = *(const ushort8*)&smem[row * 136 + col];
      *(ushort8*)(dst + (size_t)(m0 + row) * DIM + e0 + col) = v;
    }
  }
}

// ---------- kernel 2: causal flash attention, BC=64, pipelined ----------
// 512 blocks longest-first. 4 waves split D (192 each). Loop phases:
//   [softmax(t)] barrier [PV(t) + scores(t+1)] barrier
__global__ __launch_bounds__(256, 2)
void attn(const ushort* __restrict__ qb, const ushort* __restrict__ kb,
          const ushort* __restrict__ vt, float* __restrict__ out) {
  __shared__ float sred[4][32][65];       // partial scores, 64 cols + pad
  __shared__ ushort pbuf[32][72];         // P in bf16, 16B-aligned rows
  __shared__ float row_m[32], row_l[32], row_a[32];

  const int bi = blockIdx.x;
  const int b = bi & 3;
  const int j = 127 - (bi >> 2);
  const int q0 = j * 32;
  const int ntile = (j + 2) >> 1;         // ceil((j+1)/2) 64-key tiles
  const int tid = threadIdx.x;
  const int w = tid >> 6, lane = tid & 63, ln = lane & 15, quad = lane >> 4;

  const size_t qkbase = (size_t)b * SEQ * DIM;
  const size_t vtbase = (size_t)b * DIM * SEQ;
  const float scale = 0.03608439182435161f;  // 1/sqrt(768)

  short8 qf[2][6];
  {
    const ushort* qp = qb + qkbase + (size_t)(q0 + ln) * DIM + w * 192 + quad * 8;
#pragma unroll
    for (int mt = 0; mt < 2; mt++)
#pragma unroll
      for (int ks = 0; ks < 6; ks++)
        qf[mt][ks] = *(const short8*)(qp + mt * 16 * DIM + ks * 32);
  }

  fx4 acc[2][12];
#pragma unroll
  for (int mt = 0; mt < 2; mt++)
#pragma unroll
    for (int n = 0; n < 12; n++) acc[mt][n] = (fx4)0.0f;

  if (tid < 32) { row_m[tid] = -1e30f; row_l[tid] = 0.0f; }

  auto score = [&](int t) {
    const int k0 = t * 64;
    fx4 sacc[2][4];
#pragma unroll
    for (int mt = 0; mt < 2; mt++)
#pragma unroll
      for (int n = 0; n < 4; n++) sacc[mt][n] = (fx4)0.0f;
    const ushort* kp = kb + qkbase + (size_t)(k0 + ln) * DIM + w * 192 + quad * 8;
#pragma unroll
    for (int n = 0; n < 4; n++)
#pragma unroll
      for (int ks = 0; ks < 6; ks++) {
        short8 kf = *(const short8*)(kp + n * 16 * DIM + ks * 32);
        sacc[0][n] = MFMA16(qf[0][ks], kf, sacc[0][n]);
        sacc[1][n] = MFMA16(qf[1][ks], kf, sacc[1][n]);
      }
#pragma unroll
    for (int mt = 0; mt < 2; mt++)
#pragma unroll
      for (int n = 0; n < 4; n++)
#pragma unroll
        for (int r = 0; r < 4; r++)
          sred[w][mt * 16 + quad * 4 + r][n * 16 + ln] = sacc[mt][n][r];
  };

  score(0);
  __syncthreads();

  for (int t = 0; t < ntile; t++) {
    const int k0 = t * 64;
    // ---- softmax phase ----
    {
      const int row = w * 8 + (lane >> 3);
      const int cg = lane & 7;
      const int qa = q0 + row;
      float s[8];
      float tmax = -1e30f;
#pragma unroll
      for (int c = 0; c < 8; c++) {
        const int col = cg * 8 + c;
        float v = sred[0][row][col] + sred[1][row][col] + sred[2][row][col] +
                  sred[3][row][col];
        v *= scale;
        if (k0 + col > qa) v = -1e30f;
        s[c] = v;
        tmax = fmaxf(tmax, v);
      }
      tmax = fmaxf(tmax, __shfl_xor(tmax, 1));
      tmax = fmaxf(tmax, __shfl_xor(tmax, 2));
      tmax = fmaxf(tmax, __shfl_xor(tmax, 4));
      const float m_old = row_m[row];
      const float m_new = fmaxf(m_old, tmax);
      const float alpha = __expf(m_old - m_new);
      ushort8 pk;
      float psum = 0.0f;
#pragma unroll
      for (int c = 0; c < 8; c++) {
        const float p = __expf(s[c] - m_new);
        pk[c] = f2bf(p);
        psum += bf2f(pk[c]);
      }
      psum += __shfl_xor(psum, 1);
      psum += __shfl_xor(psum, 2);
      psum += __shfl_xor(psum, 4);
      if (cg == 0) {
        row_m[row] = m_new;
        row_l[row] = alpha * row_l[row] + psum;
        row_a[row] = alpha;
      }
      *(ushort8*)&pbuf[row][cg * 8] = pk;
    }
    __syncthreads();
    // ---- compute span: PV(t) + scores(t+1), no barrier between ----
    {
      float a0[4], a1[4];
      bool need = false;
#pragma unroll
      for (int r = 0; r < 4; r++) {
        a0[r] = row_a[quad * 4 + r];
        a1[r] = row_a[16 + quad * 4 + r];
        need = need || (a0[r] != 1.0f) || (a1[r] != 1.0f);
      }
      if (__any(need)) {
#pragma unroll
        for (int n = 0; n < 12; n++)
#pragma unroll
          for (int r = 0; r < 4; r++) {
            acc[0][n][r] *= a0[r];
            acc[1][n][r] *= a1[r];
          }
      }
      short8 pa[2][2];
#pragma unroll
      for (int mt = 0; mt < 2; mt++)
#pragma unroll
        for (int h = 0; h < 2; h++)
          pa[mt][h] = *(const short8*)&pbuf[mt * 16 + ln][h * 32 + quad * 8];
      const ushort* vp = vt + vtbase + (size_t)(w * 192 + ln) * SEQ + k0 + quad * 8;
#pragma unroll
      for (int n = 0; n < 12; n++) {
        short8 vf0 = *(const short8*)(vp + n * 16 * SEQ);
        short8 vf1 = *(const short8*)(vp + n * 16 * SEQ + 32);
        acc[0][n] = MFMA16(pa[0][0], vf0, acc[0][n]);
        acc[1][n] = MFMA16(pa[1][0], vf0, acc[1][n]);
        acc[0][n] = MFMA16(pa[0][1], vf1, acc[0][n]);
        acc[1][n] = MFMA16(pa[1][1], vf1, acc[1][n]);
      }
      if (t + 1 < ntile) score(t + 1);
    }
    __syncthreads();
  }

  // ---- epilogue: O / l ----
#pragma unroll
  for (int mt = 0; mt < 2; mt++)
#pragma unroll
    for (int r = 0; r < 4; r++) {
      const int row = mt * 16 + quad * 4 + r;
      const float linv = 1.0f / row_l[row];
      float* orow = out + (size_t)(b * SEQ + q0 + row) * DIM + w * 192 + ln;
#pragma unroll
      for (int n = 0; n < 12; n++) orow[n * 16] = acc[mt][n][r] * linv;
    }
}

extern "C" void kernel_launch(void* const* d_in, const int* in_sizes, int n_in,
                              void* d_out, int out_size, void* d_ws, size_t ws_size,
                              hipStream_t stream) {
  const float* x = (const float*)d_in[0];
  const float* wq = (const float*)d_in[1];
  const float* wk = (const float*)d_in[2];
  const float* wv = (const float*)d_in[3];
  float* out = (float*)d_out;

  ushort* qb = (ushort*)d_ws;
  ushort* kb = qb + 12582912;
  ushort* vt = kb + 12582912;
  ushort* xb = vt + 12582912;
  ushort* wb = xb + 12582912;

  cvt_x<<<6144, 256, 0, stream>>>(x, xb);
  cvt_w<<<864, 256, 0, stream>>>(wq, wk, wv, wb);
  qkv_proj<<<dim3(128, 18), 256, 0, stream>>>(xb, wb, qb, kb, vt);
  attn<<<512, 256, 0, stream>>>(qb, kb, vt, out);
}

// Round 3
// 371.007 us; speedup vs baseline: 2.6163x; 2.0041x over previous
//
#include <hip/hip_runtime.h>
#include <stdint.h>

// SelfAttention: B=4, S=4096, D=768, causal, fp32 in/out, bf16 MFMA compute.
// Decomposition: qkv GEMM -> scores GEMM (+exp epilogue, packed causal P tiles)
//                -> PV GEMM (/l epilogue).
// ws layout (bf16 elements):
//   qb  12582912 @ 0
//   kb  12582912 @ 12582912
//   vt  12582912 @ 25165824   [b][e][s] (V transposed)
//   xb  12582912 @ 37748736   (dead after qkv_proj)
//   wb   1769472 @ 50331648   (dead after qkv_proj)
//   pb  34603008 @ 37748736   ALIAS over xb/wb: packed causal P tiles,
//                             tile (b, mt, nt<=mt) at slot b*528+mt(mt+1)/2+nt,
//                             each 128x128 bf16 row-major
//   ls  16384 fp32 @ elem 72351744 (byte 144703488)  row sums of exp

#define SEQ 4096
#define DIM 768

typedef __attribute__((ext_vector_type(8))) short short8;
typedef __attribute__((ext_vector_type(8))) unsigned short ushort8;
typedef __attribute__((ext_vector_type(4))) unsigned short ushort4v;
typedef __attribute__((ext_vector_type(4))) float fx4;
typedef unsigned short ushort;

#define MFMA16(a, b, c) __builtin_amdgcn_mfma_f32_16x16x32_bf16((a), (b), (c), 0, 0, 0)

__device__ __forceinline__ ushort f2bf(float f) {
  union { float f; unsigned int u; } v; v.f = f;
  return (ushort)((v.u + 0x7fffu + ((v.u >> 16) & 1u)) >> 16);
}
__device__ __forceinline__ float bf2f(ushort u) {
  union { unsigned int u; float f; } v; v.u = ((unsigned int)u) << 16;
  return v.f;
}
__device__ __forceinline__ void gload_lds16(const ushort* g, ushort* l) {
  __builtin_amdgcn_global_load_lds(
      (const __attribute__((address_space(1))) void*)g,
      (__attribute__((address_space(3))) void*)l, 16, 0, 0);
}

// ---------- cvt kernels ----------
__global__ void cvt_x(const float* __restrict__ x, ushort* __restrict__ xb,
                      float* __restrict__ ls) {
  if (blockIdx.x < 64) ls[blockIdx.x * 256 + threadIdx.x] = 0.0f;  // zero row sums
  const int i = (blockIdx.x * 256 + threadIdx.x) * 8;
  fx4 a = *(const fx4*)(x + i);
  fx4 b = *(const fx4*)(x + i + 4);
  ushort8 o;
#pragma unroll
  for (int c = 0; c < 4; c++) { o[c] = f2bf(a[c]); o[c + 4] = f2bf(b[c]); }
  *(ushort8*)(xb + i) = o;
}

__global__ void cvt_w(const float* __restrict__ wq, const float* __restrict__ wk,
                      const float* __restrict__ wv, ushort* __restrict__ wb) {
  const int i = (blockIdx.x * 256 + threadIdx.x) * 8;
  const int which = i / (DIM * DIM);
  const int off = i - which * (DIM * DIM);
  const float* src = (which == 0) ? wq : (which == 1) ? wk : wv;
  fx4 a = *(const fx4*)(src + off);
  fx4 b = *(const fx4*)(src + off + 4);
  ushort8 o;
#pragma unroll
  for (int c = 0; c < 4; c++) { o[c] = f2bf(a[c]); o[c + 4] = f2bf(b[c]); }
  *(ushort8*)(wb + i) = o;
}

// ---------- kernel 1: QKV projection (m97-style 128x128 tile) ----------
__global__ __launch_bounds__(256, 4)
void qkv_proj(const ushort* __restrict__ xb, const ushort* __restrict__ wb,
              ushort* __restrict__ qb, ushort* __restrict__ kb,
              ushort* __restrict__ vt) {
  __shared__ ushort smem[17408];  // As|Bs for k-loop; ys[128][136] epilogue
  ushort* As = smem;
  ushort* Bs = smem + 4096;

  const int mb = blockIdx.x, nb = blockIdx.y;
  const int which = nb / 6;
  const int e0 = (nb % 6) * 128;
  const int m0 = mb * 128;
  const int tid = threadIdx.x;
  const int w = tid >> 6, lane = tid & 63, ln = lane & 15, quad = lane >> 4;
  const int wm = (w >> 1) * 64, wn = (w & 1) * 64;

  const ushort* W = wb + (size_t)which * (DIM * DIM);

  const int c0 = w * 128 + lane;
  const int c1 = c0 + 64;
  const int R0 = c0 >> 2, kl0 = (c0 & 3) ^ ((R0 >> 1) & 3);
  const int R1 = c1 >> 2, kl1 = (c1 & 3) ^ ((R1 >> 1) & 3);
  const ushort* ag0 = xb + (size_t)(m0 + R0) * DIM + kl0 * 8;
  const ushort* ag1 = xb + (size_t)(m0 + R1) * DIM + kl1 * 8;
  const ushort* bg0 = W + (size_t)(e0 + R0) * DIM + kl0 * 8;
  const ushort* bg1 = W + (size_t)(e0 + R1) * DIM + kl1 * 8;
  ushort* al0 = As + (size_t)(w * 128) * 8;
  ushort* al1 = As + (size_t)(w * 128 + 64) * 8;
  ushort* bl0 = Bs + (size_t)(w * 128) * 8;
  ushort* bl1 = Bs + (size_t)(w * 128 + 64) * 8;

  const int sw = quad ^ ((ln >> 1) & 3);
  int aoff[4], boff[4];
#pragma unroll
  for (int mt = 0; mt < 4; mt++) aoff[mt] = ((wm + mt * 16 + ln) * 4 + sw) * 8;
#pragma unroll
  for (int nt = 0; nt < 4; nt++) boff[nt] = ((wn + nt * 16 + ln) * 4 + sw) * 8;

  fx4 acc[4][4];
#pragma unroll
  for (int mt = 0; mt < 4; mt++)
#pragma unroll
    for (int nt = 0; nt < 4; nt++) acc[mt][nt] = (fx4)0.0f;

  for (int kk = 0; kk < DIM; kk += 32) {
    gload_lds16(ag0 + kk, al0);
    gload_lds16(ag1 + kk, al1);
    gload_lds16(bg0 + kk, bl0);
    gload_lds16(bg1 + kk, bl1);
    __syncthreads();
    short8 af[4], bf[4];
#pragma unroll
    for (int mt = 0; mt < 4; mt++) af[mt] = *(const short8*)(As + aoff[mt]);
#pragma unroll
    for (int nt = 0; nt < 4; nt++) bf[nt] = *(const short8*)(Bs + boff[nt]);
#pragma unroll
    for (int mt = 0; mt < 4; mt++)
#pragma unroll
      for (int nt = 0; nt < 4; nt++)
        acc[mt][nt] = MFMA16(af[mt], bf[nt], acc[mt][nt]);
    __syncthreads();
  }

  if (which == 2) {
#pragma unroll
    for (int mt = 0; mt < 4; mt++)
#pragma unroll
      for (int nt = 0; nt < 4; nt++) {
        const int s = m0 + wm + mt * 16 + quad * 4;
        const int e = e0 + wn + nt * 16 + ln;
        const int bb = s >> 12, si = s & 4095;
        ushort4v p;
#pragma unroll
        for (int r = 0; r < 4; r++) p[r] = f2bf(acc[mt][nt][r]);
        *(ushort4v*)(vt + ((size_t)bb * DIM + e) * SEQ + si) = p;
      }
  } else {
#pragma unroll
    for (int mt = 0; mt < 4; mt++)
#pragma unroll
      for (int nt = 0; nt < 4; nt++)
#pragma unroll
        for (int r = 0; r < 4; r++)
          smem[(wm + mt * 16 + quad * 4 + r) * 136 + wn + nt * 16 + ln] =
              f2bf(acc[mt][nt][r]);
    __syncthreads();
    ushort* dst = (which == 0) ? qb : kb;
#pragma unroll
    for (int p = 0; p < 8; p++) {
      const int tt = p * 256 + tid;
      const int row = tt >> 4, col = (tt & 15) * 8;
      ushort8 v = *(const ushort8*)&smem[row * 136 + col];
      *(ushort8*)(dst + (size_t)(m0 + row) * DIM + e0 + col) = v;
    }
  }
}

// ---------- kernel 2: scores GEMM + exp epilogue ----------
// grid (528, 4): x = causal tile pair (mt, nt<=mt), y = batch.
// P_hat[q][k] = exp(scale * q.k) (0 above diagonal); row sums -> atomicAdd ls.
__global__ __launch_bounds__(256, 4)
void attn_scores(const ushort* __restrict__ qb, const ushort* __restrict__ kb,
                 ushort* __restrict__ pb, float* __restrict__ ls) {
  __shared__ ushort smem[17408];
  ushort* As = smem;
  ushort* Bs = smem + 4096;

  const int pr = blockIdx.x;
  const int b = blockIdx.y;
  int mt = (int)(0.5f * (sqrtf(8.0f * pr + 1.0f) - 1.0f));
  while ((mt + 1) * (mt + 2) / 2 <= pr) ++mt;
  while (mt * (mt + 1) / 2 > pr) --mt;
  const int nt = pr - mt * (mt + 1) / 2;
  const int m0 = mt * 128, n0 = nt * 128;

  const int tid = threadIdx.x;
  const int w = tid >> 6, lane = tid & 63, ln = lane & 15, quad = lane >> 4;
  const int wm = (w >> 1) * 64, wn = (w & 1) * 64;
  const size_t qkbase = (size_t)b * SEQ * DIM;
  const float scale = 0.03608439182435161f;  // 1/sqrt(768)

  const int c0 = w * 128 + lane;
  const int c1 = c0 + 64;
  const int R0 = c0 >> 2, kl0 = (c0 & 3) ^ ((R0 >> 1) & 3);
  const int R1 = c1 >> 2, kl1 = (c1 & 3) ^ ((R1 >> 1) & 3);
  const ushort* ag0 = qb + qkbase + (size_t)(m0 + R0) * DIM + kl0 * 8;
  const ushort* ag1 = qb + qkbase + (size_t)(m0 + R1) * DIM + kl1 * 8;
  const ushort* bg0 = kb + qkbase + (size_t)(n0 + R0) * DIM + kl0 * 8;
  const ushort* bg1 = kb + qkbase + (size_t)(n0 + R1) * DIM + kl1 * 8;
  ushort* al0 = As + (size_t)(w * 128) * 8;
  ushort* al1 = As + (size_t)(w * 128 + 64) * 8;
  ushort* bl0 = Bs + (size_t)(w * 128) * 8;
  ushort* bl1 = Bs + (size_t)(w * 128 + 64) * 8;

  const int sw = quad ^ ((ln >> 1) & 3);
  int aoff[4], boff[4];
#pragma unroll
  for (int i = 0; i < 4; i++) aoff[i] = ((wm + i * 16 + ln) * 4 + sw) * 8;
#pragma unroll
  for (int i = 0; i < 4; i++) boff[i] = ((wn + i * 16 + ln) * 4 + sw) * 8;

  fx4 acc[4][4];
#pragma unroll
  for (int i = 0; i < 4; i++)
#pragma unroll
    for (int j = 0; j < 4; j++) acc[i][j] = (fx4)0.0f;

  for (int kk = 0; kk < DIM; kk += 32) {
    gload_lds16(ag0 + kk, al0);
    gload_lds16(ag1 + kk, al1);
    gload_lds16(bg0 + kk, bl0);
    gload_lds16(bg1 + kk, bl1);
    __syncthreads();
    short8 af[4], bf[4];
#pragma unroll
    for (int i = 0; i < 4; i++) af[i] = *(const short8*)(As + aoff[i]);
#pragma unroll
    for (int i = 0; i < 4; i++) bf[i] = *(const short8*)(Bs + boff[i]);
#pragma unroll
    for (int i = 0; i < 4; i++)
#pragma unroll
      for (int j = 0; j < 4; j++)
        acc[i][j] = MFMA16(af[i], bf[j], acc[i][j]);
    __syncthreads();
  }

  // epilogue: exp + mask + row sums + pack to LDS
  float rowp[4][4];  // [i_mt][r] partial row sums over this wave's 64 cols
#pragma unroll
  for (int i = 0; i < 4; i++) {
#pragma unroll
    for (int r = 0; r < 4; r++) rowp[i][r] = 0.0f;
#pragma unroll
    for (int j = 0; j < 4; j++) {
      const int col = n0 + wn + j * 16 + ln;
#pragma unroll
      for (int r = 0; r < 4; r++) {
        const int row = m0 + wm + i * 16 + quad * 4 + r;
        float p = 0.0f;
        if (col <= row) p = __expf(acc[i][j][r] * scale);
        const ushort pk = f2bf(p);
        smem[(wm + i * 16 + quad * 4 + r) * 136 + wn + j * 16 + ln] = pk;
        rowp[i][r] += bf2f(pk);
      }
    }
  }
  // reduce row sums across the 16 ln-lanes of each quad, then atomicAdd
#pragma unroll
  for (int i = 0; i < 4; i++)
#pragma unroll
    for (int r = 0; r < 4; r++) {
      float s = rowp[i][r];
      s += __shfl_xor(s, 1);
      s += __shfl_xor(s, 2);
      s += __shfl_xor(s, 4);
      s += __shfl_xor(s, 8);
      if (ln == 0)
        atomicAdd(ls + b * SEQ + m0 + wm + i * 16 + quad * 4 + r, s);
    }
  __syncthreads();
  // coalesced 16B stores into packed tile
  ushort* pt = pb + ((size_t)(b * 528 + pr) << 14);
#pragma unroll
  for (int p = 0; p < 8; p++) {
    const int tt = p * 256 + tid;
    const int row = tt >> 4, col = (tt & 15) * 8;
    ushort8 v = *(const ushort8*)&smem[row * 136 + col];
    *(ushort8*)(pt + row * 128 + col) = v;
  }
}

// ---------- kernel 3: O = P_hat @ V, divide by l ----------
// grid 768 linear, longest K first: mt = 31 - idx/24; rem: b = rem&3, et = rem>>2.
__global__ __launch_bounds__(256, 4)
void attn_pv(const ushort* __restrict__ pb, const ushort* __restrict__ vt,
             const float* __restrict__ ls, float* __restrict__ out) {
  __shared__ ushort smem[8192];
  ushort* As = smem;
  ushort* Bs = smem + 4096;

  const int idx = blockIdx.x;
  const int mt = 31 - idx / 24;
  const int rem = idx % 24;
  const int b = rem & 3;
  const int et = rem >> 2;
  const int m0 = mt * 128, e0 = et * 128;

  const int tid = threadIdx.x;
  const int w = tid >> 6, lane = tid & 63, ln = lane & 15, quad = lane >> 4;
  const int wm = (w >> 1) * 64, wn = (w & 1) * 64;
  const size_t vtbase = (size_t)b * DIM * SEQ;
  const ushort* ptiles = pb + ((size_t)(b * 528 + mt * (mt + 1) / 2) << 14);

  const int c0 = w * 128 + lane;
  const int c1 = c0 + 64;
  const int R0 = c0 >> 2, kl0 = (c0 & 3) ^ ((R0 >> 1) & 3);
  const int R1 = c1 >> 2, kl1 = (c1 & 3) ^ ((R1 >> 1) & 3);
  // A: packed P tile, row stride 128. B: vt rows (e0+R), col = k.
  const ushort* ag0 = ptiles + R0 * 128 + kl0 * 8;
  const ushort* ag1 = ptiles + R1 * 128 + kl1 * 8;
  const ushort* bg0 = vt + vtbase + (size_t)(e0 + R0) * SEQ + kl0 * 8;
  const ushort* bg1 = vt + vtbase + (size_t)(e0 + R1) * SEQ + kl1 * 8;
  ushort* al0 = As + (size_t)(w * 128) * 8;
  ushort* al1 = As + (size_t)(w * 128 + 64) * 8;
  ushort* bl0 = Bs + (size_t)(w * 128) * 8;
  ushort* bl1 = Bs + (size_t)(w * 128 + 64) * 8;

  const int sw = quad ^ ((ln >> 1) & 3);
  int aoff[4], boff[4];
#pragma unroll
  for (int i = 0; i < 4; i++) aoff[i] = ((wm + i * 16 + ln) * 4 + sw) * 8;
#pragma unroll
  for (int i = 0; i < 4; i++) boff[i] = ((wn + i * 16 + ln) * 4 + sw) * 8;

  fx4 acc[4][4];
#pragma unroll
  for (int i = 0; i < 4; i++)
#pragma unroll
    for (int j = 0; j < 4; j++) acc[i][j] = (fx4)0.0f;

  const int nk = (mt + 1) * 4;  // 32-wide k-steps
  for (int ks = 0; ks < nk; ks++) {
    const int ntile = ks >> 2;           // which P tile
    const int kin = (ks & 3) * 32;       // k offset within tile
    const size_t atile = (size_t)ntile * 16384 + kin;
    const int kglob = ntile * 128 + kin; // k offset in vt
    gload_lds16(ag0 + atile, al0);
    gload_lds16(ag1 + atile, al1);
    gload_lds16(bg0 + kglob, bl0);
    gload_lds16(bg1 + kglob, bl1);
    __syncthreads();
    short8 af[4], bf[4];
#pragma unroll
    for (int i = 0; i < 4; i++) af[i] = *(const short8*)(As + aoff[i]);
#pragma unroll
    for (int i = 0; i < 4; i++) bf[i] = *(const short8*)(Bs + boff[i]);
#pragma unroll
    for (int i = 0; i < 4; i++)
#pragma unroll
      for (int j = 0; j < 4; j++)
        acc[i][j] = MFMA16(af[i], bf[j], acc[i][j]);
    __syncthreads();
  }

  // epilogue: divide by row sum, store fp32
#pragma unroll
  for (int i = 0; i < 4; i++)
#pragma unroll
    for (int r = 0; r < 4; r++) {
      const int row = m0 + wm + i * 16 + quad * 4 + r;
      const float linv = 1.0f / ls[b * SEQ + row];
      float* orow = out + ((size_t)(b * SEQ + row)) * DIM + e0 + wn + ln;
#pragma unroll
      for (int j = 0; j < 4; j++) orow[j * 16] = acc[i][j][r] * linv;
    }
}

extern "C" void kernel_launch(void* const* d_in, const int* in_sizes, int n_in,
                              void* d_out, int out_size, void* d_ws, size_t ws_size,
                              hipStream_t stream) {
  const float* x = (const float*)d_in[0];
  const float* wq = (const float*)d_in[1];
  const float* wk = (const float*)d_in[2];
  const float* wv = (const float*)d_in[3];
  float* out = (float*)d_out;

  ushort* qb = (ushort*)d_ws;
  ushort* kb = qb + 12582912;
  ushort* vt = kb + 12582912;
  ushort* xb = vt + 12582912;
  ushort* wb = xb + 12582912;
  ushort* pb = xb;  // alias: xb/wb dead after qkv_proj
  float* ls = (float*)((ushort*)d_ws + 72351744);

  cvt_x<<<6144, 256, 0, stream>>>(x, xb, ls);
  cvt_w<<<864, 256, 0, stream>>>(wq, wk, wv, wb);
  qkv_proj<<<dim3(128, 18), 256, 0, stream>>>(xb, wb, qb, kb, vt);
  attn_scores<<<dim3(528, 4), 256, 0, stream>>>(qb, kb, pb, ls);
  attn_pv<<<768, 256, 0, stream>>>(pb, vt, ls, out);
}

// Round 4
// 349.391 us; speedup vs baseline: 2.7781x; 1.0619x over previous
//
#include <hip/hip_runtime.h>
#include <stdint.h>

// SelfAttention: B=4, S=4096, D=768, causal, fp32 in/out, bf16 MFMA compute.
// Decomposition: cvt -> qkv GEMM -> scores GEMM (+exp epilogue, packed causal
// P tiles) -> PV GEMM (/l epilogue). All GEMMs: 128x128 tile, BK=64 (two
// BK=32 XOR-swizzled panels per barrier pair), global_load_lds width-16.
// ws layout (bf16 elements):
//   qb  12582912 @ 0
//   kb  12582912 @ 12582912
//   vt  12582912 @ 25165824   [b][e][s] (V transposed)
//   xb  12582912 @ 37748736   (dead after qkv_proj)
//   wb   1769472 @ 50331648   (dead after qkv_proj)
//   pb  34603008 @ 37748736   ALIAS over xb/wb: packed causal P tiles,
//                             tile (b, mt, nt<=mt) at slot b*528+mt(mt+1)/2+nt
//   ls  16384 fp32 @ elem 72351744
#define SEQ 4096
#define DIM 768

typedef __attribute__((ext_vector_type(8))) short short8;
typedef __attribute__((ext_vector_type(8))) unsigned short ushort8;
typedef __attribute__((ext_vector_type(4))) unsigned short ushort4v;
typedef __attribute__((ext_vector_type(4))) float fx4;
typedef unsigned short ushort;

#define MFMA16(a, b, c) __builtin_amdgcn_mfma_f32_16x16x32_bf16((a), (b), (c), 0, 0, 0)

__device__ __forceinline__ ushort f2bf(float f) {
  union { float f; unsigned int u; } v; v.f = f;
  return (ushort)((v.u + 0x7fffu + ((v.u >> 16) & 1u)) >> 16);
}
__device__ __forceinline__ float bf2f(ushort u) {
  union { unsigned int u; float f; } v; v.u = ((unsigned int)u) << 16;
  return v.f;
}
__device__ __forceinline__ void gload_lds16(const ushort* g, ushort* l) {
  __builtin_amdgcn_global_load_lds(
      (const __attribute__((address_space(1))) void*)g,
      (__attribute__((address_space(3))) void*)l, 16, 0, 0);
}

// ---------- kernel 0: fused fp32->bf16 casts + ls zero ----------
__global__ void cvt_all(const float* __restrict__ x, const float* __restrict__ wq,
                        const float* __restrict__ wk, const float* __restrict__ wv,
                        ushort* __restrict__ xb, ushort* __restrict__ wb,
                        float* __restrict__ ls) {
  const int bid = blockIdx.x;
  if (bid < 6144) {
    if (bid < 64) ls[bid * 256 + threadIdx.x] = 0.0f;
    const int i = (bid * 256 + threadIdx.x) * 8;
    fx4 a = *(const fx4*)(x + i);
    fx4 b = *(const fx4*)(x + i + 4);
    ushort8 o;
#pragma unroll
    for (int c = 0; c < 4; c++) { o[c] = f2bf(a[c]); o[c + 4] = f2bf(b[c]); }
    *(ushort8*)(xb + i) = o;
  } else {
    const int i = ((bid - 6144) * 256 + threadIdx.x) * 8;
    const int which = i / (DIM * DIM);
    const int off = i - which * (DIM * DIM);
    const float* src = (which == 0) ? wq : (which == 1) ? wk : wv;
    fx4 a = *(const fx4*)(src + off);
    fx4 b = *(const fx4*)(src + off + 4);
    ushort8 o;
#pragma unroll
    for (int c = 0; c < 4; c++) { o[c] = f2bf(a[c]); o[c + 4] = f2bf(b[c]); }
    *(ushort8*)(wb + i) = o;
  }
}

// ---------- kernel 1: QKV projection (128x128 tile, BK=64) ----------
__global__ __launch_bounds__(256, 4)
void qkv_proj(const ushort* __restrict__ xb, const ushort* __restrict__ wb,
              ushort* __restrict__ qb, ushort* __restrict__ kb,
              ushort* __restrict__ vt) {
  __shared__ ushort smem[17408];  // k-loop: As[8192]|Bs[8192]; epilogue 128x136
  ushort* As = smem;
  ushort* Bs = smem + 8192;

  const int mb = blockIdx.x, nb = blockIdx.y;
  const int which = nb / 6;
  const int e0 = (nb % 6) * 128;
  const int m0 = mb * 128;
  const int tid = threadIdx.x;
  const int w = tid >> 6, lane = tid & 63, ln = lane & 15, quad = lane >> 4;
  const int wm = (w >> 1) * 64, wn = (w & 1) * 64;

  const ushort* W = wb + (size_t)which * (DIM * DIM);

  // per-panel staging: chunk c -> row R=c>>2, k-group kl=(c&3)^((R>>1)&3)
  const int c0 = w * 128 + lane;
  const int c1 = c0 + 64;
  const int R0 = c0 >> 2, kl0 = (c0 & 3) ^ ((R0 >> 1) & 3);
  const int R1 = c1 >> 2, kl1 = (c1 & 3) ^ ((R1 >> 1) & 3);
  const ushort* ag0 = xb + (size_t)(m0 + R0) * DIM + kl0 * 8;
  const ushort* ag1 = xb + (size_t)(m0 + R1) * DIM + kl1 * 8;
  const ushort* bg0 = W + (size_t)(e0 + R0) * DIM + kl0 * 8;
  const ushort* bg1 = W + (size_t)(e0 + R1) * DIM + kl1 * 8;
  ushort* al0 = As + (size_t)(w * 128) * 8;
  ushort* al1 = As + (size_t)(w * 128 + 64) * 8;
  ushort* bl0 = Bs + (size_t)(w * 128) * 8;
  ushort* bl1 = Bs + (size_t)(w * 128 + 64) * 8;

  const int sw = quad ^ ((ln >> 1) & 3);
  int aoff[4], boff[4];
#pragma unroll
  for (int i = 0; i < 4; i++) aoff[i] = ((wm + i * 16 + ln) * 4 + sw) * 8;
#pragma unroll
  for (int i = 0; i < 4; i++) boff[i] = ((wn + i * 16 + ln) * 4 + sw) * 8;

  fx4 acc[4][4];
#pragma unroll
  for (int i = 0; i < 4; i++)
#pragma unroll
    for (int j = 0; j < 4; j++) acc[i][j] = (fx4)0.0f;

  for (int kk = 0; kk < DIM; kk += 64) {
    gload_lds16(ag0 + kk, al0);
    gload_lds16(ag1 + kk, al1);
    gload_lds16(ag0 + kk + 32, al0 + 4096);
    gload_lds16(ag1 + kk + 32, al1 + 4096);
    gload_lds16(bg0 + kk, bl0);
    gload_lds16(bg1 + kk, bl1);
    gload_lds16(bg0 + kk + 32, bl0 + 4096);
    gload_lds16(bg1 + kk + 32, bl1 + 4096);
    __syncthreads();
#pragma unroll
    for (int h = 0; h < 2; h++) {
      const int hb = h * 4096;
      short8 af[4], bf[4];
#pragma unroll
      for (int i = 0; i < 4; i++) af[i] = *(const short8*)(As + hb + aoff[i]);
#pragma unroll
      for (int i = 0; i < 4; i++) bf[i] = *(const short8*)(Bs + hb + boff[i]);
#pragma unroll
      for (int i = 0; i < 4; i++)
#pragma unroll
        for (int j = 0; j < 4; j++)
          acc[i][j] = MFMA16(af[i], bf[j], acc[i][j]);
    }
    __syncthreads();
  }

  if (which == 2) {
#pragma unroll
    for (int i = 0; i < 4; i++)
#pragma unroll
      for (int j = 0; j < 4; j++) {
        const int s = m0 + wm + i * 16 + quad * 4;
        const int e = e0 + wn + j * 16 + ln;
        const int bb = s >> 12, si = s & 4095;
        ushort4v p;
#pragma unroll
        for (int r = 0; r < 4; r++) p[r] = f2bf(acc[i][j][r]);
        *(ushort4v*)(vt + ((size_t)bb * DIM + e) * SEQ + si) = p;
      }
  } else {
#pragma unroll
    for (int i = 0; i < 4; i++)
#pragma unroll
      for (int j = 0; j < 4; j++)
#pragma unroll
        for (int r = 0; r < 4; r++)
          smem[(wm + i * 16 + quad * 4 + r) * 136 + wn + j * 16 + ln] =
              f2bf(acc[i][j][r]);
    __syncthreads();
    ushort* dst = (which == 0) ? qb : kb;
#pragma unroll
    for (int p = 0; p < 8; p++) {
      const int tt = p * 256 + tid;
      const int row = tt >> 4, col = (tt & 15) * 8;
      ushort8 v = *(const ushort8*)&smem[row * 136 + col];
      *(ushort8*)(dst + (size_t)(m0 + row) * DIM + e0 + col) = v;
    }
  }
}

// ---------- kernel 2: scores GEMM + exp epilogue (BK=64) ----------
__global__ __launch_bounds__(256, 4)
void attn_scores(const ushort* __restrict__ qb, const ushort* __restrict__ kb,
                 ushort* __restrict__ pb, float* __restrict__ ls) {
  __shared__ ushort smem[17408];
  ushort* As = smem;
  ushort* Bs = smem + 8192;

  const int pr = blockIdx.x;
  const int b = blockIdx.y;
  int mt = (int)(0.5f * (sqrtf(8.0f * pr + 1.0f) - 1.0f));
  while ((mt + 1) * (mt + 2) / 2 <= pr) ++mt;
  while (mt * (mt + 1) / 2 > pr) --mt;
  const int nt = pr - mt * (mt + 1) / 2;
  const int m0 = mt * 128, n0 = nt * 128;

  const int tid = threadIdx.x;
  const int w = tid >> 6, lane = tid & 63, ln = lane & 15, quad = lane >> 4;
  const int wm = (w >> 1) * 64, wn = (w & 1) * 64;
  const size_t qkbase = (size_t)b * SEQ * DIM;
  const float scale = 0.03608439182435161f;  // 1/sqrt(768)

  const int c0 = w * 128 + lane;
  const int c1 = c0 + 64;
  const int R0 = c0 >> 2, kl0 = (c0 & 3) ^ ((R0 >> 1) & 3);
  const int R1 = c1 >> 2, kl1 = (c1 & 3) ^ ((R1 >> 1) & 3);
  const ushort* ag0 = qb + qkbase + (size_t)(m0 + R0) * DIM + kl0 * 8;
  const ushort* ag1 = qb + qkbase + (size_t)(m0 + R1) * DIM + kl1 * 8;
  const ushort* bg0 = kb + qkbase + (size_t)(n0 + R0) * DIM + kl0 * 8;
  const ushort* bg1 = kb + qkbase + (size_t)(n0 + R1) * DIM + kl1 * 8;
  ushort* al0 = As + (size_t)(w * 128) * 8;
  ushort* al1 = As + (size_t)(w * 128 + 64) * 8;
  ushort* bl0 = Bs + (size_t)(w * 128) * 8;
  ushort* bl1 = Bs + (size_t)(w * 128 + 64) * 8;

  const int sw = quad ^ ((ln >> 1) & 3);
  int aoff[4], boff[4];
#pragma unroll
  for (int i = 0; i < 4; i++) aoff[i] = ((wm + i * 16 + ln) * 4 + sw) * 8;
#pragma unroll
  for (int i = 0; i < 4; i++) boff[i] = ((wn + i * 16 + ln) * 4 + sw) * 8;

  fx4 acc[4][4];
#pragma unroll
  for (int i = 0; i < 4; i++)
#pragma unroll
    for (int j = 0; j < 4; j++) acc[i][j] = (fx4)0.0f;

  for (int kk = 0; kk < DIM; kk += 64) {
    gload_lds16(ag0 + kk, al0);
    gload_lds16(ag1 + kk, al1);
    gload_lds16(ag0 + kk + 32, al0 + 4096);
    gload_lds16(ag1 + kk + 32, al1 + 4096);
    gload_lds16(bg0 + kk, bl0);
    gload_lds16(bg1 + kk, bl1);
    gload_lds16(bg0 + kk + 32, bl0 + 4096);
    gload_lds16(bg1 + kk + 32, bl1 + 4096);
    __syncthreads();
#pragma unroll
    for (int h = 0; h < 2; h++) {
      const int hb = h * 4096;
      short8 af[4], bf[4];
#pragma unroll
      for (int i = 0; i < 4; i++) af[i] = *(const short8*)(As + hb + aoff[i]);
#pragma unroll
      for (int i = 0; i < 4; i++) bf[i] = *(const short8*)(Bs + hb + boff[i]);
#pragma unroll
      for (int i = 0; i < 4; i++)
#pragma unroll
        for (int j = 0; j < 4; j++)
          acc[i][j] = MFMA16(af[i], bf[j], acc[i][j]);
    }
    __syncthreads();
  }

  // epilogue: exp + causal mask + row sums + pack via LDS
  float rowp[4][4];
#pragma unroll
  for (int i = 0; i < 4; i++) {
#pragma unroll
    for (int r = 0; r < 4; r++) rowp[i][r] = 0.0f;
#pragma unroll
    for (int j = 0; j < 4; j++) {
      const int col = n0 + wn + j * 16 + ln;
#pragma unroll
      for (int r = 0; r < 4; r++) {
        const int row = m0 + wm + i * 16 + quad * 4 + r;
        float p = 0.0f;
        if (col <= row) p = __expf(acc[i][j][r] * scale);
        const ushort pk = f2bf(p);
        smem[(wm + i * 16 + quad * 4 + r) * 136 + wn + j * 16 + ln] = pk;
        rowp[i][r] += bf2f(pk);
      }
    }
  }
#pragma unroll
  for (int i = 0; i < 4; i++)
#pragma unroll
    for (int r = 0; r < 4; r++) {
      float s = rowp[i][r];
      s += __shfl_xor(s, 1);
      s += __shfl_xor(s, 2);
      s += __shfl_xor(s, 4);
      s += __shfl_xor(s, 8);
      if (ln == 0)
        atomicAdd(ls + b * SEQ + m0 + wm + i * 16 + quad * 4 + r, s);
    }
  __syncthreads();
  ushort* pt = pb + ((size_t)(b * 528 + pr) << 14);
#pragma unroll
  for (int p = 0; p < 8; p++) {
    const int tt = p * 256 + tid;
    const int row = tt >> 4, col = (tt & 15) * 8;
    ushort8 v = *(const ushort8*)&smem[row * 136 + col];
    *(ushort8*)(pt + row * 128 + col) = v;
  }
}

// ---------- kernel 3: O = P_hat @ V, divide by l (BK=64, serpentine) ----------
__global__ __launch_bounds__(256, 4)
void attn_pv(const ushort* __restrict__ pb, const ushort* __restrict__ vt,
             const float* __restrict__ ls, float* __restrict__ out) {
  __shared__ ushort smem[16384];
  ushort* As = smem;
  ushort* Bs = smem + 8192;

  // serpentine rank -> (mt desc, et, b): balances per-CU work at 3 blocks/CU
  int idx = blockIdx.x;
  int chunk = idx >> 8, pos = idx & 255;
  if (chunk & 1) pos = 255 - pos;
  const int r_ = (chunk << 8) + pos;
  const int mt = 31 - r_ / 24;
  const int rem = r_ % 24;
  const int b = rem & 3;
  const int et = rem >> 2;
  const int m0 = mt * 128, e0 = et * 128;

  const int tid = threadIdx.x;
  const int w = tid >> 6, lane = tid & 63, ln = lane & 15, quad = lane >> 4;
  const int wm = (w >> 1) * 64, wn = (w & 1) * 64;
  const size_t vtbase = (size_t)b * DIM * SEQ;
  const ushort* ptiles = pb + ((size_t)(b * 528 + mt * (mt + 1) / 2) << 14);

  const int c0 = w * 128 + lane;
  const int c1 = c0 + 64;
  const int R0 = c0 >> 2, kl0 = (c0 & 3) ^ ((R0 >> 1) & 3);
  const int R1 = c1 >> 2, kl1 = (c1 & 3) ^ ((R1 >> 1) & 3);
  const ushort* ag0 = ptiles + R0 * 128 + kl0 * 8;
  const ushort* ag1 = ptiles + R1 * 128 + kl1 * 8;
  const ushort* bg0 = vt + vtbase + (size_t)(e0 + R0) * SEQ + kl0 * 8;
  const ushort* bg1 = vt + vtbase + (size_t)(e0 + R1) * SEQ + kl1 * 8;
  ushort* al0 = As + (size_t)(w * 128) * 8;
  ushort* al1 = As + (size_t)(w * 128 + 64) * 8;
  ushort* bl0 = Bs + (size_t)(w * 128) * 8;
  ushort* bl1 = Bs + (size_t)(w * 128 + 64) * 8;

  const int sw = quad ^ ((ln >> 1) & 3);
  int aoff[4], boff[4];
#pragma unroll
  for (int i = 0; i < 4; i++) aoff[i] = ((wm + i * 16 + ln) * 4 + sw) * 8;
#pragma unroll
  for (int i = 0; i < 4; i++) boff[i] = ((wn + i * 16 + ln) * 4 + sw) * 8;

  fx4 acc[4][4];
#pragma unroll
  for (int i = 0; i < 4; i++)
#pragma unroll
    for (int j = 0; j < 4; j++) acc[i][j] = (fx4)0.0f;

  const int nk = (mt + 1) * 2;  // 64-wide k-steps
  for (int ks = 0; ks < nk; ks++) {
    const int ntile = ks >> 1;
    const int kin = (ks & 1) * 64;
    const size_t atile = (size_t)ntile * 16384 + kin;
    const int kglob = ntile * 128 + kin;
    gload_lds16(ag0 + atile, al0);
    gload_lds16(ag1 + atile, al1);
    gload_lds16(ag0 + atile + 32, al0 + 4096);
    gload_lds16(ag1 + atile + 32, al1 + 4096);
    gload_lds16(bg0 + kglob, bl0);
    gload_lds16(bg1 + kglob, bl1);
    gload_lds16(bg0 + kglob + 32, bl0 + 4096);
    gload_lds16(bg1 + kglob + 32, bl1 + 4096);
    __syncthreads();
#pragma unroll
    for (int h = 0; h < 2; h++) {
      const int hb = h * 4096;
      short8 af[4], bf[4];
#pragma unroll
      for (int i = 0; i < 4; i++) af[i] = *(const short8*)(As + hb + aoff[i]);
#pragma unroll
      for (int i = 0; i < 4; i++) bf[i] = *(const short8*)(Bs + hb + boff[i]);
#pragma unroll
      for (int i = 0; i < 4; i++)
#pragma unroll
        for (int j = 0; j < 4; j++)
          acc[i][j] = MFMA16(af[i], bf[j], acc[i][j]);
    }
    __syncthreads();
  }

#pragma unroll
  for (int i = 0; i < 4; i++)
#pragma unroll
    for (int r = 0; r < 4; r++) {
      const int row = m0 + wm + i * 16 + quad * 4 + r;
      const float linv = 1.0f / ls[b * SEQ + row];
      float* orow = out + ((size_t)(b * SEQ + row)) * DIM + e0 + wn + ln;
#pragma unroll
      for (int j = 0; j < 4; j++) orow[j * 16] = acc[i][j][r] * linv;
    }
}

extern "C" void kernel_launch(void* const* d_in, const int* in_sizes, int n_in,
                              void* d_out, int out_size, void* d_ws, size_t ws_size,
                              hipStream_t stream) {
  const float* x = (const float*)d_in[0];
  const float* wq = (const float*)d_in[1];
  const float* wk = (const float*)d_in[2];
  const float* wv = (const float*)d_in[3];
  float* out = (float*)d_out;

  ushort* qb = (ushort*)d_ws;
  ushort* kb = qb + 12582912;
  ushort* vt = kb + 12582912;
  ushort* xb = vt + 12582912;
  ushort* wb = xb + 12582912;
  ushort* pb = xb;  // alias: xb/wb dead after qkv_proj
  float* ls = (float*)((ushort*)d_ws + 72351744);

  cvt_all<<<7008, 256, 0, stream>>>(x, wq, wk, wv, xb, wb, ls);
  qkv_proj<<<dim3(128, 18), 256, 0, stream>>>(xb, wb, qb, kb, vt);
  attn_scores<<<dim3(528, 4), 256, 0, stream>>>(qb, kb, pb, ls);
  attn_pv<<<768, 256, 0, stream>>>(pb, vt, ls, out);
}